// Round 13
// baseline (115.301 us; speedup 1.0000x reference)
//
#include <hip/hip_runtime.h>
#include <hip/hip_bf16.h>

namespace {
constexpr int AH = 9, AW = 9, NS = AH * AW;   // 81 samples per ROI
constexpr int C = 256, H = 64, W = 64, HW = H * W;
constexpr float SCALE = 0.0625f;
constexpr int ELEMS = C * NS;                 // 20736 outputs per ROI
constexpr int SPW = 11;                       // samples per wave (8*11 >= 81)
constexpr int SLAB4 = 64 * NS / 4;            // 1296 f32x4 per 64-ch slab
}

typedef float f32x4 __attribute__((ext_vector_type(4)));

__device__ __forceinline__ float bf_lo(unsigned u) { return __uint_as_float(u << 16); }
__device__ __forceinline__ float bf_hi(unsigned u) { return __uint_as_float(u & 0xffff0000u); }

// ---------- pass 1: NCHW f32 -> NHWC bf16 into workspace ----------
__global__ __launch_bounds__(256)
void nchw_to_nhwc_bf16_kernel(const float* __restrict__ in,
                              ushort* __restrict__ out)
{
    __shared__ float tile[64][33];
    const int b  = blockIdx.z;
    const int p0 = blockIdx.x * 32;
    const int c0 = blockIdx.y * 64;
    const float* src = in + (size_t)b * C * HW;
    ushort*      dst = out + (size_t)b * HW * C;
    const int tx = threadIdx.x;   // 0..31
    const int ty = threadIdx.y;   // 0..7
    #pragma unroll
    for (int k = 0; k < 8; ++k)
        tile[ty + 8 * k][tx] = src[(size_t)(c0 + ty + 8 * k) * HW + p0 + tx];
    __syncthreads();
    #pragma unroll
    for (int k = 0; k < 4; ++k) {
        const int p = ty + 8 * k;             // 0..31
        __hip_bfloat16 lo = __float2bfloat16(tile[2 * tx][p]);
        __hip_bfloat16 hi = __float2bfloat16(tile[2 * tx + 1][p]);
        ushort2 u;
        u.x = *reinterpret_cast<ushort*>(&lo);
        u.y = *reinterpret_cast<ushort*>(&hi);
        *reinterpret_cast<ushort2*>(dst + (size_t)(p0 + p) * C + c0 + 2 * tx) = u;
    }
}

// ---------- pass 2: ROI align, one block per ROI, software-pipelined --------
// 512 thr / 8 waves; wave owns 11 samples; lane owns 2 channels per half.
// 4 slab rounds (h0g0,h0g1,h1g0,h1g1); h1 gather overlaps h0g1 store.
__global__ __launch_bounds__(512, 8)
void rod_align_pipe_kernel(const ushort* __restrict__ nhwc,
                           const float* __restrict__ rois,
                           float* __restrict__ out)
{
    __shared__ float4 s_w[NS];
    __shared__ int    s_o[NS];                // (y0*W + x0) * C/2  (dword units)
    __shared__ float  s_buf[64 * NS];         // flat [cc*81 + ss] == output slab

    const int r    = blockIdx.x;
    const int t    = threadIdx.x;
    const int wave = t >> 6;                  // 0..7
    const int lane = t & 63;

    const float* roi = rois + r * 5;
    const int   b  = (int)roi[0];
    const float x1 = roi[1] * SCALE;
    const float y1 = roi[2] * SCALE;
    const float x2 = roi[3] * SCALE;
    const float y2 = roi[4] * SCALE;
    const float bin_h = (y2 - y1) * 0.125f;
    const float bin_w = (x2 - x1) * 0.125f;

    if (t < NS) {
        const int i = t / AW;
        const int j = t - i * AW;
        const float Y = y1 + (float)i * bin_h;
        const float X = x1 + (float)j * bin_w;
        const bool valid = (Y >= 0.f) && (Y < (float)H) &&
                           (X >= 0.f) && (X < (float)W);
        const float fy = fminf(fmaxf(floorf(Y), 0.f), (float)(H - 2));
        const float fx = fminf(fmaxf(floorf(X), 0.f), (float)(W - 2));
        const float ly = Y - fy, lx = X - fx;
        const float hy = 1.f - ly, hx = 1.f - lx;
        const float v = valid ? 1.f : 0.f;
        s_o[t] = ((int)fy * W + (int)fx) * (C / 2);
        s_w[t] = make_float4(hy * hx * v, hy * lx * v, ly * hx * v, ly * lx * v);
    }
    __syncthreads();

    const unsigned* __restrict__ pd0 =
        reinterpret_cast<const unsigned*>(nhwc + (size_t)b * (HW * C)) + lane;
    const unsigned* __restrict__ pd1 = pd0 + 64;      // channels 128..255
    float* __restrict__ ob = out + (size_t)r * ELEMS;

    const int s0 = wave * SPW;
    const f32x4* __restrict__ sb4 = reinterpret_cast<const f32x4*>(s_buf);

    float accA[SPW][2];
    float accB[SPW][2];

    // macro-ish helpers via lambdas (all compile-time unrolled, static indices)
    #define GATHER(acc, pd, ibeg, iend)                                        \
        _Pragma("unroll")                                                      \
        for (int i = (ibeg); i < (iend); ++i) {                                \
            int s = s0 + i; if (s > NS - 1) s = NS - 1;                        \
            const int o = s_o[s];                                              \
            const unsigned q00 = (pd)[o];                                      \
            const unsigned q01 = (pd)[o + 128];                                \
            const unsigned q10 = (pd)[o + 8192];                               \
            const unsigned q11 = (pd)[o + 8320];                               \
            const float4 w4 = s_w[s];                                          \
            acc[i][0] = bf_lo(q00) * w4.x + bf_lo(q01) * w4.y                  \
                      + bf_lo(q10) * w4.z + bf_lo(q11) * w4.w;                 \
            acc[i][1] = bf_hi(q00) * w4.x + bf_hi(q01) * w4.y                  \
                      + bf_hi(q10) * w4.z + bf_hi(q11) * w4.w;                 \
        }

    #define XCHG(acc, g)                                                       \
        if ((lane >> 5) == (g)) {                                              \
            const int kk = (lane & 31) * 2;                                    \
            _Pragma("unroll")                                                  \
            for (int i = 0; i < SPW; ++i) {                                    \
                int s = s0 + i; if (s > NS - 1) s = NS - 1;                    \
                s_buf[kk * NS + s]       = acc[i][0];                          \
                s_buf[(kk + 1) * NS + s] = acc[i][1];                          \
            }                                                                  \
        }

    #define STORE(cbase, fbeg, fend)                                           \
        {                                                                      \
            f32x4* __restrict__ oc4 =                                          \
                reinterpret_cast<f32x4*>(ob + (cbase) * NS);                   \
            for (int f = (fbeg) + t; f < (fend); f += 512)                     \
                __builtin_nontemporal_store(sb4[f], &oc4[f]);                  \
        }

    // ---- h0: gather, then rounds g0, g1 ----
    GATHER(accA, pd0, 0, SPW)

    XCHG(accA, 0)
    __syncthreads();
    STORE(0, 0, SLAB4)
    __syncthreads();                          // s_buf consumed

    XCHG(accA, 1)
    __syncthreads();

    // ---- pipelined: store h0g1 slab interleaved with h1 gather ----
    GATHER(accB, pd1, 0, 6)
    STORE(64, 0, SLAB4 / 2)
    GATHER(accB, pd1, 6, SPW)
    STORE(64, SLAB4 / 2, SLAB4)
    __syncthreads();                          // s_buf consumed

    // ---- h1 rounds g0, g1 ----
    XCHG(accB, 0)
    __syncthreads();
    STORE(128, 0, SLAB4)
    __syncthreads();

    XCHG(accB, 1)
    __syncthreads();
    STORE(192, 0, SLAB4)

    #undef GATHER
    #undef XCHG
    #undef STORE
}

// ---------- fallback: direct NCHW f32 ----------
__global__ __launch_bounds__(256, 8)
void rod_align_nchw_kernel(const float* __restrict__ feat,
                           const float* __restrict__ rois,
                           float* __restrict__ out)
{
    __shared__ float4 s_w[NS];
    __shared__ int    s_off[NS];

    const int r = blockIdx.x;
    const int t = threadIdx.x;

    const float* roi = rois + r * 5;
    const int   b  = (int)roi[0];
    const float x1 = roi[1] * SCALE;
    const float y1 = roi[2] * SCALE;
    const float x2 = roi[3] * SCALE;
    const float y2 = roi[4] * SCALE;
    const float bin_h = (y2 - y1) * 0.125f;
    const float bin_w = (x2 - x1) * 0.125f;

    if (t < NS) {
        const int i = t / AW;
        const int j = t - i * AW;
        const float Y = y1 + (float)i * bin_h;
        const float X = x1 + (float)j * bin_w;
        const bool valid = (Y >= 0.f) && (Y < (float)H) &&
                           (X >= 0.f) && (X < (float)W);
        const float fy = fminf(fmaxf(floorf(Y), 0.f), (float)(H - 2));
        const float fx = fminf(fmaxf(floorf(X), 0.f), (float)(W - 2));
        const float ly = Y - fy, lx = X - fx;
        const float hy = 1.f - ly, hx = 1.f - lx;
        const float v = valid ? 1.f : 0.f;
        s_off[t] = (int)fy * W + (int)fx;
        s_w[t] = make_float4(hy * hx * v, hy * lx * v, ly * hx * v, ly * lx * v);
    }
    __syncthreads();

    const float* __restrict__ fb = feat + (size_t)b * (C * HW);
    float* __restrict__ ob = out + (size_t)r * ELEMS;

    int c = t / NS;
    int s = t - c * NS;
    #pragma unroll 3
    for (int it = 0; it < NS; ++it) {
        const int off = (c << 12) + s_off[s];
        const float4 w = s_w[s];
        const float f00 = fb[off];
        const float f01 = fb[off + 1];
        const float f10 = fb[off + W];
        const float f11 = fb[off + W + 1];
        ob[t + (it << 8)] = f00 * w.x + f01 * w.y + f10 * w.z + f11 * w.w;
        c += 3; s += 13;
        if (s >= NS) { s -= NS; ++c; }
    }
}

extern "C" void kernel_launch(void* const* d_in, const int* in_sizes, int n_in,
                              void* d_out, int out_size, void* d_ws, size_t ws_size,
                              hipStream_t stream) {
    const float* feat = (const float*)d_in[0];
    const float* rois = (const float*)d_in[1];
    float* outp = (float*)d_out;
    const int R = in_sizes[1] / 5;            // 2048
    const int B = in_sizes[0] / (C * HW);     // 4

    const size_t nhwc_bytes = (size_t)B * HW * C * sizeof(ushort);

    if (ws_size >= nhwc_bytes) {
        ushort* nhwc = (ushort*)d_ws;
        dim3 tgrid(HW / 32, C / 64, B);
        dim3 tblk(32, 8);
        nchw_to_nhwc_bf16_kernel<<<tgrid, tblk, 0, stream>>>(feat, nhwc);
        rod_align_pipe_kernel<<<R, 512, 0, stream>>>(nhwc, rois, outp);
    } else {
        rod_align_nchw_kernel<<<R, 256, 0, stream>>>(feat, rois, outp);
    }
}

// Round 14
// 54.410 us; speedup vs baseline: 2.1191x; 2.1191x over previous
//
#include <hip/hip_runtime.h>
#include <hip/hip_bf16.h>

namespace {
constexpr int AH = 9, AW = 9, NS = AH * AW;   // 81 samples per ROI
constexpr int C = 256, H = 64, W = 64, HW = H * W;
constexpr float SCALE = 0.0625f;
constexpr int ELEMS = C * NS;                 // 20736 outputs per ROI
constexpr int SPW = 11;                       // samples per wave (8*11 >= 81)
}

typedef float f32x4 __attribute__((ext_vector_type(4)));

__device__ __forceinline__ float bf_lo(unsigned u) { return __uint_as_float(u << 16); }
__device__ __forceinline__ float bf_hi(unsigned u) { return __uint_as_float(u & 0xffff0000u); }

// ---------- pass 0: batch-grouped ROI permutation (temporal L2 locality) ----
__global__ __launch_bounds__(256)
void build_perm_kernel(const float* __restrict__ rois, int R,
                       int* __restrict__ perm)
{
    __shared__ int cnt[4];
    __shared__ int base[4];
    const int t = threadIdx.x;
    if (t < 4) cnt[t] = 0;
    __syncthreads();
    for (int r = t; r < R; r += 256)
        atomicAdd(&cnt[(int)rois[r * 5]], 1);
    __syncthreads();
    if (t == 0) {
        base[0] = 0;
        base[1] = cnt[0];
        base[2] = cnt[0] + cnt[1];
        base[3] = cnt[0] + cnt[1] + cnt[2];
    }
    __syncthreads();
    if (t < 4) cnt[t] = 0;                    // reuse as cursors
    __syncthreads();
    for (int r = t; r < R; r += 256) {
        const int b = (int)rois[r * 5];
        const int k = atomicAdd(&cnt[b], 1);
        perm[base[b] + k] = r;                // grouping only; order within batch
    }                                         // is irrelevant to output values
}

// ---------- pass 1: NCHW f32 -> NHWC bf16 into workspace ----------
__global__ __launch_bounds__(256)
void nchw_to_nhwc_bf16_kernel(const float* __restrict__ in,
                              ushort* __restrict__ out)
{
    __shared__ float tile[64][33];
    const int b  = blockIdx.z;
    const int p0 = blockIdx.x * 32;
    const int c0 = blockIdx.y * 64;
    const float* src = in + (size_t)b * C * HW;
    ushort*      dst = out + (size_t)b * HW * C;
    const int tx = threadIdx.x;   // 0..31
    const int ty = threadIdx.y;   // 0..7
    #pragma unroll
    for (int k = 0; k < 8; ++k)
        tile[ty + 8 * k][tx] = src[(size_t)(c0 + ty + 8 * k) * HW + p0 + tx];
    __syncthreads();
    #pragma unroll
    for (int k = 0; k < 4; ++k) {
        const int p = ty + 8 * k;             // 0..31
        __hip_bfloat16 lo = __float2bfloat16(tile[2 * tx][p]);
        __hip_bfloat16 hi = __float2bfloat16(tile[2 * tx + 1][p]);
        ushort2 u;
        u.x = *reinterpret_cast<ushort*>(&lo);
        u.y = *reinterpret_cast<ushort*>(&hi);
        *reinterpret_cast<ushort2*>(dst + (size_t)(p0 + p) * C + c0 + 2 * tx) = u;
    }
}

// ---------- pass 2: ROI align, 512-thread block per (ROI, 128-ch half) ------
// Round-12 structure exactly; ROI index comes from the batch-grouped perm so
// contemporaneous blocks share one ~2 MB batch slab (fits every XCD L2).
__global__ __launch_bounds__(512, 8)
void rod_align_half8_kernel(const ushort* __restrict__ nhwc,
                            const float* __restrict__ rois,
                            const int* __restrict__ perm,
                            float* __restrict__ out)
{
    __shared__ float4 s_w[NS];
    __shared__ int    s_o[NS];                // (y0*W + x0) * C/2  (dword units)
    __shared__ float  s_buf[64 * NS];         // flat [cc*81 + ss] == output slab

    const int r    = perm[blockIdx.x >> 1];
    const int half = blockIdx.x & 1;
    const int t    = threadIdx.x;
    const int wave = t >> 6;                  // 0..7
    const int lane = t & 63;

    const float* roi = rois + r * 5;
    const int   b  = (int)roi[0];
    const float x1 = roi[1] * SCALE;
    const float y1 = roi[2] * SCALE;
    const float x2 = roi[3] * SCALE;
    const float y2 = roi[4] * SCALE;
    const float bin_h = (y2 - y1) * 0.125f;
    const float bin_w = (x2 - x1) * 0.125f;

    if (t < NS) {
        const int i = t / AW;
        const int j = t - i * AW;
        const float Y = y1 + (float)i * bin_h;
        const float X = x1 + (float)j * bin_w;
        const bool valid = (Y >= 0.f) && (Y < (float)H) &&
                           (X >= 0.f) && (X < (float)W);
        const float fy = fminf(fmaxf(floorf(Y), 0.f), (float)(H - 2));
        const float fx = fminf(fmaxf(floorf(X), 0.f), (float)(W - 2));
        const float ly = Y - fy, lx = X - fx;
        const float hy = 1.f - ly, hx = 1.f - lx;
        const float v = valid ? 1.f : 0.f;
        s_o[t] = ((int)fy * W + (int)fx) * (C / 2);
        s_w[t] = make_float4(hy * hx * v, hy * lx * v, ly * hx * v, ly * lx * v);
    }
    __syncthreads();

    // dword view: 2 bf16 channels per lane; half selects channels 128*half..+127
    const unsigned* __restrict__ pd =
        reinterpret_cast<const unsigned*>(nhwc + (size_t)b * (HW * C)) + half * 64 + lane;
    float* __restrict__ ob = out + (size_t)r * ELEMS;

    const int s0 = wave * SPW;
    float acc[SPW][2];

    #pragma unroll
    for (int i = 0; i < SPW; ++i) {
        int s = s0 + i; if (s > NS - 1) s = NS - 1;   // wave-7 tail: benign repeats
        const int o = s_o[s];
        const unsigned q00 = pd[o];
        const unsigned q01 = pd[o + 128];      // x+1:  +C/2 dwords
        const unsigned q10 = pd[o + 8192];     // y+1:  +W*C/2 dwords
        const unsigned q11 = pd[o + 8320];
        const float4 w4 = s_w[s];
        acc[i][0] = bf_lo(q00) * w4.x + bf_lo(q01) * w4.y
                  + bf_lo(q10) * w4.z + bf_lo(q11) * w4.w;
        acc[i][1] = bf_hi(q00) * w4.x + bf_hi(q01) * w4.y
                  + bf_hi(q10) * w4.z + bf_hi(q11) * w4.w;
    }

    // 2 rounds: channels 64g..64g+63 (of this half) held by lanes 32g..32g+31
    #pragma unroll 1
    for (int g = 0; g < 2; ++g) {
        __syncthreads();                      // s_buf free (prev round consumed)
        if ((lane >> 5) == g) {
            const int kk = (lane & 31) * 2;   // channel rows kk, kk+1
            #pragma unroll
            for (int i = 0; i < SPW; ++i) {
                int s = s0 + i; if (s > NS - 1) s = NS - 1;
                s_buf[kk * NS + s]       = acc[i][0];
                s_buf[(kk + 1) * NS + s] = acc[i][1];
            }
        }
        __syncthreads();
        // contiguous 5184-dword slab == flat s_buf: float4 nt stores
        f32x4* __restrict__ oc4 =
            reinterpret_cast<f32x4*>(ob + (half * 128 + g * 64) * NS);
        const f32x4* __restrict__ sb4 = reinterpret_cast<const f32x4*>(s_buf);
        for (int f = t; f < (64 * NS) / 4; f += 512)   // 1296 float4s
            __builtin_nontemporal_store(sb4[f], &oc4[f]);
    }
}

// ---------- fallback: direct NCHW f32 ----------
__global__ __launch_bounds__(256, 8)
void rod_align_nchw_kernel(const float* __restrict__ feat,
                           const float* __restrict__ rois,
                           float* __restrict__ out)
{
    __shared__ float4 s_w[NS];
    __shared__ int    s_off[NS];

    const int r = blockIdx.x;
    const int t = threadIdx.x;

    const float* roi = rois + r * 5;
    const int   b  = (int)roi[0];
    const float x1 = roi[1] * SCALE;
    const float y1 = roi[2] * SCALE;
    const float x2 = roi[3] * SCALE;
    const float y2 = roi[4] * SCALE;
    const float bin_h = (y2 - y1) * 0.125f;
    const float bin_w = (x2 - x1) * 0.125f;

    if (t < NS) {
        const int i = t / AW;
        const int j = t - i * AW;
        const float Y = y1 + (float)i * bin_h;
        const float X = x1 + (float)j * bin_w;
        const bool valid = (Y >= 0.f) && (Y < (float)H) &&
                           (X >= 0.f) && (X < (float)W);
        const float fy = fminf(fmaxf(floorf(Y), 0.f), (float)(H - 2));
        const float fx = fminf(fmaxf(floorf(X), 0.f), (float)(W - 2));
        const float ly = Y - fy, lx = X - fx;
        const float hy = 1.f - ly, hx = 1.f - lx;
        const float v = valid ? 1.f : 0.f;
        s_off[t] = (int)fy * W + (int)fx;
        s_w[t] = make_float4(hy * hx * v, hy * lx * v, ly * hx * v, ly * lx * v);
    }
    __syncthreads();

    const float* __restrict__ fb = feat + (size_t)b * (C * HW);
    float* __restrict__ ob = out + (size_t)r * ELEMS;

    int c = t / NS;
    int s = t - c * NS;
    #pragma unroll 3
    for (int it = 0; it < NS; ++it) {
        const int off = (c << 12) + s_off[s];
        const float4 w = s_w[s];
        const float f00 = fb[off];
        const float f01 = fb[off + 1];
        const float f10 = fb[off + W];
        const float f11 = fb[off + W + 1];
        ob[t + (it << 8)] = f00 * w.x + f01 * w.y + f10 * w.z + f11 * w.w;
        c += 3; s += 13;
        if (s >= NS) { s -= NS; ++c; }
    }
}

extern "C" void kernel_launch(void* const* d_in, const int* in_sizes, int n_in,
                              void* d_out, int out_size, void* d_ws, size_t ws_size,
                              hipStream_t stream) {
    const float* feat = (const float*)d_in[0];
    const float* rois = (const float*)d_in[1];
    float* outp = (float*)d_out;
    const int R = in_sizes[1] / 5;            // 2048
    const int B = in_sizes[0] / (C * HW);     // 4

    const size_t nhwc_bytes = (size_t)B * HW * C * sizeof(ushort);
    const size_t perm_bytes = (size_t)R * sizeof(int);

    if (B == 4 && ws_size >= nhwc_bytes + perm_bytes) {
        ushort* nhwc = (ushort*)d_ws;
        int*    perm = (int*)((char*)d_ws + nhwc_bytes);

        build_perm_kernel<<<1, 256, 0, stream>>>(rois, R, perm);
        dim3 tgrid(HW / 32, C / 64, B);
        dim3 tblk(32, 8);
        nchw_to_nhwc_bf16_kernel<<<tgrid, tblk, 0, stream>>>(feat, nhwc);
        rod_align_half8_kernel<<<2 * R, 512, 0, stream>>>(nhwc, rois, perm, outp);
    } else {
        rod_align_nchw_kernel<<<R, 256, 0, stream>>>(feat, rois, outp);
    }
}

// Round 15
// 43.284 us; speedup vs baseline: 2.6638x; 1.2571x over previous
//
#include <hip/hip_runtime.h>
#include <hip/hip_bf16.h>

namespace {
constexpr int AH = 9, AW = 9, NS = AH * AW;   // 81 samples per ROI
constexpr int C = 256, H = 64, W = 64, HW = H * W;
constexpr float SCALE = 0.0625f;
constexpr int ELEMS = C * NS;                 // 20736 outputs per ROI
constexpr int SPW = 11;                       // samples per wave (8*11 >= 81)
}

typedef float f32x4 __attribute__((ext_vector_type(4)));   // native vec for nt-store

__device__ __forceinline__ float bf_lo(unsigned u) { return __uint_as_float(u << 16); }
__device__ __forceinline__ float bf_hi(unsigned u) { return __uint_as_float(u & 0xffff0000u); }

// ---------- pass 1: NCHW f32 -> NHWC bf16 into workspace ----------
__global__ __launch_bounds__(256)
void nchw_to_nhwc_bf16_kernel(const float* __restrict__ in,
                              ushort* __restrict__ out)
{
    __shared__ float tile[64][33];
    const int b  = blockIdx.z;
    const int p0 = blockIdx.x * 32;
    const int c0 = blockIdx.y * 64;
    const float* src = in + (size_t)b * C * HW;
    ushort*      dst = out + (size_t)b * HW * C;
    const int tx = threadIdx.x;   // 0..31
    const int ty = threadIdx.y;   // 0..7
    #pragma unroll
    for (int k = 0; k < 8; ++k)
        tile[ty + 8 * k][tx] = src[(size_t)(c0 + ty + 8 * k) * HW + p0 + tx];
    __syncthreads();
    #pragma unroll
    for (int k = 0; k < 4; ++k) {
        const int p = ty + 8 * k;             // 0..31
        __hip_bfloat16 lo = __float2bfloat16(tile[2 * tx][p]);
        __hip_bfloat16 hi = __float2bfloat16(tile[2 * tx + 1][p]);
        ushort2 u;
        u.x = *reinterpret_cast<ushort*>(&lo);
        u.y = *reinterpret_cast<ushort*>(&hi);
        *reinterpret_cast<ushort2*>(dst + (size_t)(p0 + p) * C + c0 + 2 * tx) = u;
    }
}

// ---------- pass 2: ROI align, 512-thread block per (ROI, 128-ch half) ------
// 8 waves; wave owns 11 samples; lane owns 2 channels (dword gathers).
// Round-12 optimum: nt stores + flat channel-major LDS buffer -> f32x4 stores.
__global__ __launch_bounds__(512, 8)
void rod_align_half8_kernel(const ushort* __restrict__ nhwc,
                            const float* __restrict__ rois,
                            float* __restrict__ out)
{
    __shared__ float4 s_w[NS];
    __shared__ int    s_o[NS];                // (y0*W + x0) * C/2  (dword units)
    __shared__ float  s_buf[64 * NS];         // flat [cc*81 + ss] == output slab

    const int r    = blockIdx.x >> 1;
    const int half = blockIdx.x & 1;
    const int t    = threadIdx.x;
    const int wave = t >> 6;                  // 0..7
    const int lane = t & 63;

    const float* roi = rois + r * 5;
    const int   b  = (int)roi[0];
    const float x1 = roi[1] * SCALE;
    const float y1 = roi[2] * SCALE;
    const float x2 = roi[3] * SCALE;
    const float y2 = roi[4] * SCALE;
    const float bin_h = (y2 - y1) * 0.125f;
    const float bin_w = (x2 - x1) * 0.125f;

    if (t < NS) {
        const int i = t / AW;
        const int j = t - i * AW;
        const float Y = y1 + (float)i * bin_h;
        const float X = x1 + (float)j * bin_w;
        const bool valid = (Y >= 0.f) && (Y < (float)H) &&
                           (X >= 0.f) && (X < (float)W);
        const float fy = fminf(fmaxf(floorf(Y), 0.f), (float)(H - 2));
        const float fx = fminf(fmaxf(floorf(X), 0.f), (float)(W - 2));
        const float ly = Y - fy, lx = X - fx;
        const float hy = 1.f - ly, hx = 1.f - lx;
        const float v = valid ? 1.f : 0.f;
        s_o[t] = ((int)fy * W + (int)fx) * (C / 2);
        s_w[t] = make_float4(hy * hx * v, hy * lx * v, ly * hx * v, ly * lx * v);
    }
    __syncthreads();

    // dword view: 2 bf16 channels per lane; half selects channels 128*half..+127
    const unsigned* __restrict__ pd =
        reinterpret_cast<const unsigned*>(nhwc + (size_t)b * (HW * C)) + half * 64 + lane;
    float* __restrict__ ob = out + (size_t)r * ELEMS;

    const int s0 = wave * SPW;
    float acc[SPW][2];

    #pragma unroll
    for (int i = 0; i < SPW; ++i) {
        int s = s0 + i; if (s > NS - 1) s = NS - 1;   // wave-7 tail: benign repeats
        const int o = s_o[s];
        const unsigned q00 = pd[o];
        const unsigned q01 = pd[o + 128];      // x+1:  +C/2 dwords
        const unsigned q10 = pd[o + 8192];     // y+1:  +W*C/2 dwords
        const unsigned q11 = pd[o + 8320];
        const float4 w4 = s_w[s];
        acc[i][0] = bf_lo(q00) * w4.x + bf_lo(q01) * w4.y
                  + bf_lo(q10) * w4.z + bf_lo(q11) * w4.w;
        acc[i][1] = bf_hi(q00) * w4.x + bf_hi(q01) * w4.y
                  + bf_hi(q10) * w4.z + bf_hi(q11) * w4.w;
    }

    // 2 rounds: channels 64g..64g+63 (of this half) held by lanes 32g..32g+31
    #pragma unroll 1
    for (int g = 0; g < 2; ++g) {
        __syncthreads();                      // s_buf free (prev round consumed)
        if ((lane >> 5) == g) {
            const int kk = (lane & 31) * 2;   // channel rows kk, kk+1
            #pragma unroll
            for (int i = 0; i < SPW; ++i) {
                int s = s0 + i; if (s > NS - 1) s = NS - 1;
                s_buf[kk * NS + s]       = acc[i][0];
                s_buf[(kk + 1) * NS + s] = acc[i][1];
            }
        }
        __syncthreads();
        // contiguous 5184-dword slab == flat s_buf: float4 nt stores
        f32x4* __restrict__ oc4 =
            reinterpret_cast<f32x4*>(ob + (half * 128 + g * 64) * NS);
        const f32x4* __restrict__ sb4 = reinterpret_cast<const f32x4*>(s_buf);
        for (int f = t; f < (64 * NS) / 4; f += 512)   // 1296 float4s
            __builtin_nontemporal_store(sb4[f], &oc4[f]);
    }
}

// ---------- fallback: direct NCHW f32 ----------
__global__ __launch_bounds__(256, 8)
void rod_align_nchw_kernel(const float* __restrict__ feat,
                           const float* __restrict__ rois,
                           float* __restrict__ out)
{
    __shared__ float4 s_w[NS];
    __shared__ int    s_off[NS];

    const int r = blockIdx.x;
    const int t = threadIdx.x;

    const float* roi = rois + r * 5;
    const int   b  = (int)roi[0];
    const float x1 = roi[1] * SCALE;
    const float y1 = roi[2] * SCALE;
    const float x2 = roi[3] * SCALE;
    const float y2 = roi[4] * SCALE;
    const float bin_h = (y2 - y1) * 0.125f;
    const float bin_w = (x2 - x1) * 0.125f;

    if (t < NS) {
        const int i = t / AW;
        const int j = t - i * AW;
        const float Y = y1 + (float)i * bin_h;
        const float X = x1 + (float)j * bin_w;
        const bool valid = (Y >= 0.f) && (Y < (float)H) &&
                           (X >= 0.f) && (X < (float)W);
        const float fy = fminf(fmaxf(floorf(Y), 0.f), (float)(H - 2));
        const float fx = fminf(fmaxf(floorf(X), 0.f), (float)(W - 2));
        const float ly = Y - fy, lx = X - fx;
        const float hy = 1.f - ly, hx = 1.f - lx;
        const float v = valid ? 1.f : 0.f;
        s_off[t] = (int)fy * W + (int)fx;
        s_w[t] = make_float4(hy * hx * v, hy * lx * v, ly * hx * v, ly * lx * v);
    }
    __syncthreads();

    const float* __restrict__ fb = feat + (size_t)b * (C * HW);
    float* __restrict__ ob = out + (size_t)r * ELEMS;

    int c = t / NS;
    int s = t - c * NS;
    #pragma unroll 3
    for (int it = 0; it < NS; ++it) {
        const int off = (c << 12) + s_off[s];
        const float4 w = s_w[s];
        const float f00 = fb[off];
        const float f01 = fb[off + 1];
        const float f10 = fb[off + W];
        const float f11 = fb[off + W + 1];
        ob[t + (it << 8)] = f00 * w.x + f01 * w.y + f10 * w.z + f11 * w.w;
        c += 3; s += 13;
        if (s >= NS) { s -= NS; ++c; }
    }
}

extern "C" void kernel_launch(void* const* d_in, const int* in_sizes, int n_in,
                              void* d_out, int out_size, void* d_ws, size_t ws_size,
                              hipStream_t stream) {
    const float* feat = (const float*)d_in[0];
    const float* rois = (const float*)d_in[1];
    float* outp = (float*)d_out;
    const int R = in_sizes[1] / 5;            // 2048
    const int B = in_sizes[0] / (C * HW);     // 4

    const size_t nhwc_bytes = (size_t)B * HW * C * sizeof(ushort);

    if (ws_size >= nhwc_bytes) {
        ushort* nhwc = (ushort*)d_ws;
        dim3 tgrid(HW / 32, C / 64, B);
        dim3 tblk(32, 8);
        nchw_to_nhwc_bf16_kernel<<<tgrid, tblk, 0, stream>>>(feat, nhwc);
        rod_align_half8_kernel<<<2 * R, 512, 0, stream>>>(nhwc, rois, outp);
    } else {
        rod_align_nchw_kernel<<<R, 256, 0, stream>>>(feat, rois, outp);
    }
}